// Round 11
// baseline (352.232 us; speedup 1.0000x reference)
//
#include <hip/hip_runtime.h>
#include <math.h>

#define S_LEN 512
#define D_IN  768
#define H_DIM 50
#define G4    200
#define NCT   13
#define BROWS 128
#define NTILES 1024      // (256*512)/128
#define KSTEPS 24        // 768/32
#define FR_KS  13312     // ushorts per K-step of frag-packed W (26,624 B)

typedef float   f32x4 __attribute__((ext_vector_type(4)));
typedef short   s16x8 __attribute__((ext_vector_type(8)));
typedef _Float16 f16x2 __attribute__((ext_vector_type(2)));

__device__ ushort g_Wf[KSTEPS * FR_KS];   // [ks][ct][half][lane][8]
__device__ int    g_counter;

#define LOG2E 1.44269504f

__device__ __forceinline__ float fexp2(float x) {
#if __has_builtin(__builtin_amdgcn_exp2f)
    return __builtin_amdgcn_exp2f(x);
#else
    return exp2f(x);
#endif
}
__device__ __forceinline__ float frcp(float x) {
#if __has_builtin(__builtin_amdgcn_rcpf)
    return __builtin_amdgcn_rcpf(x);
#else
    return 1.0f / x;
#endif
}
__device__ __forceinline__ float fsigmoid(float x) {
    return frcp(1.0f + fexp2(-LOG2E * x));
}
__device__ __forceinline__ float ftanh(float x) {
    float ax = __builtin_fabsf(x);
    float e  = fexp2(-2.0f * LOG2E * ax);
    float t  = (1.0f - e) * frcp(1.0f + e);
    return __builtin_copysignf(t, x);
}

// ---------------------------------------------------------------------------
// prep: pack W_ih into MFMA-frag-linear bf16 hi/lo: g_Wf[ks][ct][half][lane][8]
// ---------------------------------------------------------------------------
__global__ void prep_w(const float* __restrict__ W) {
    int f = blockIdx.x * 256 + threadIdx.x;          // frag id
    if (f == 0) g_counter = 0;
    if (f >= KSTEPS * 26 * 64) return;               // 39936 frags
    const int l  = f & 63;
    const int g  = (f >> 6) % 26;
    const int ks = (f >> 6) / 26;
    const int ct = g >> 1, hf = g & 1;
    const int n  = ct * 16 + (l & 15);
    const int k0 = ks * 32 + (l >> 4) * 8;
    ushort v[8] __attribute__((aligned(16)));
#pragma unroll
    for (int j = 0; j < 8; ++j) v[j] = 0;
    if (n < G4) {
        const float* wp = &W[(size_t)n * D_IN + k0];
#pragma unroll
        for (int j = 0; j < 8; ++j) {
            float xv = wp[j];
            unsigned u = __float_as_uint(xv);
            if (hf == 0) v[j] = (ushort)(u >> 16);
            else {
                float d = xv - __uint_as_float(u & 0xffff0000u);
                v[j] = (ushort)(__float_as_uint(d) >> 16);
            }
        }
    }
    *(uint4*)&g_Wf[(size_t)f * 8] = *(const uint4*)v;
}

__device__ __forceinline__ void pack2(float f0, float f1, unsigned& h, unsigned& l) {
    unsigned u0 = __float_as_uint(f0), u1 = __float_as_uint(f1);
    h = (u0 >> 16) | (u1 & 0xffff0000u);
    float d0 = f0 - __uint_as_float(u0 & 0xffff0000u);
    float d1 = f1 - __uint_as_float(u1 & 0xffff0000u);
    l = (__float_as_uint(d0) >> 16) | (__float_as_uint(d1) & 0xffff0000u);
}

// async-stage one K-step of packed W into LDS (26,624 B).
__device__ __forceinline__ void stage_b(int ks, ushort* dst, int wv, int lane) {
    const ushort* gb = g_Wf + (size_t)ks * FR_KS;
#pragma unroll
    for (int i = 0; i < 7; ++i) {
        const int c0 = i * 2048 + wv * 512;          // ushort units
        if (c0 < FR_KS) {
#if __has_builtin(__builtin_amdgcn_global_load_lds)
            __builtin_amdgcn_global_load_lds(
                (const __attribute__((address_space(1))) unsigned int*)(gb + c0 + lane * 8),
                (__attribute__((address_space(3))) unsigned int*)(dst + c0),
                16, 0, 0);
#else
            *(uint4*)(dst + c0 + (size_t)lane * 8) = *(const uint4*)(gb + c0 + (size_t)lane * 8);
#endif
        }
    }
}

// ---------------------------------------------------------------------------
// xg = x @ W_ih^T (+ bias, fused into epilogue), split-bf16 MFMA. Unchanged.
// ---------------------------------------------------------------------------
__global__ __launch_bounds__(256, 2) void gemm_xg(
    const float* __restrict__ x, const int* __restrict__ mask,
    const float* __restrict__ b_ih, const float* __restrict__ b_hh,
    float* __restrict__ xg)
{
    __shared__ ushort Bs[2][FR_KS];                  // 53,248 B
    __shared__ int tile_sh;
    const int tid  = threadIdx.x;
    const int wv   = tid >> 6;
    const int lane = tid & 63;
    const int lr   = lane & 15;
    const int kch  = (lane >> 4) * 8;

    for (;;) {
        if (tid == 0) tile_sh = atomicAdd(&g_counter, 1);
        __syncthreads();
        const int tile = tile_sh;
        __syncthreads();
        if (tile >= NTILES) return;

        const int row0 = tile * BROWS;
        const int b    = row0 >> 9;
        const int t0   = row0 & (S_LEN - 1);
        if (mask[b * S_LEN + t0] == 0) continue;     // whole tile past length[b]
        const bool live = mask[b * S_LEN + t0 + wv * 32] != 0;

        const int r0 = row0 + wv * 32;
        const float* xr0 = x + (size_t)(r0 + lr) * D_IN;
        const float* xr1 = xr0 + (size_t)16 * D_IN;

        f32x4 acc0[NCT], acc1[NCT];
#pragma unroll
        for (int i = 0; i < NCT; ++i) {
            acc0[i] = (f32x4){0.f, 0.f, 0.f, 0.f};
            acc1[i] = (f32x4){0.f, 0.f, 0.f, 0.f};
        }
        float4 ac0 = {0,0,0,0}, ac1 = {0,0,0,0}, ac2 = {0,0,0,0}, ac3 = {0,0,0,0};
        float4 an0 = {0,0,0,0}, an1 = {0,0,0,0}, an2 = {0,0,0,0}, an3 = {0,0,0,0};

        stage_b(0, Bs[0], wv, lane);
        if (live) {
            ac0 = *(const float4*)(xr0 + kch);
            ac1 = *(const float4*)(xr0 + kch + 4);
            ac2 = *(const float4*)(xr1 + kch);
            ac3 = *(const float4*)(xr1 + kch + 4);
        }
        __syncthreads();                             // Bs[0] staged & drained

        for (int ks = 0; ks < KSTEPS; ++ks) {
            if (ks < KSTEPS - 1) {
                stage_b(ks + 1, Bs[(ks + 1) & 1], wv, lane);
                if (live) {
                    const int k1 = (ks + 1) * 32 + kch;
                    an0 = *(const float4*)(xr0 + k1);
                    an1 = *(const float4*)(xr0 + k1 + 4);
                    an2 = *(const float4*)(xr1 + k1);
                    an3 = *(const float4*)(xr1 + k1 + 4);
                }
            }
            if (live) {
                uint4 h0, l0, h1, l1;
                pack2(ac0.x, ac0.y, h0.x, l0.x); pack2(ac0.z, ac0.w, h0.y, l0.y);
                pack2(ac1.x, ac1.y, h0.z, l0.z); pack2(ac1.z, ac1.w, h0.w, l0.w);
                pack2(ac2.x, ac2.y, h1.x, l1.x); pack2(ac2.z, ac2.w, h1.y, l1.y);
                pack2(ac3.x, ac3.y, h1.z, l1.z); pack2(ac3.z, ac3.w, h1.w, l1.w);
                s16x8 A0h = *(s16x8*)&h0, A0l = *(s16x8*)&l0;
                s16x8 A1h = *(s16x8*)&h1, A1l = *(s16x8*)&l1;
                const ushort* bp = &Bs[ks & 1][lane * 8];
#pragma unroll
                for (int ct = 0; ct < NCT; ++ct) {
                    s16x8 Bh = *(const s16x8*)(bp + ct * 1024);
                    s16x8 Bl = *(const s16x8*)(bp + ct * 1024 + 512);
                    acc0[ct] = __builtin_amdgcn_mfma_f32_16x16x32_bf16(A0h, Bh, acc0[ct], 0, 0, 0);
                    acc0[ct] = __builtin_amdgcn_mfma_f32_16x16x32_bf16(A0l, Bh, acc0[ct], 0, 0, 0);
                    acc0[ct] = __builtin_amdgcn_mfma_f32_16x16x32_bf16(A0h, Bl, acc0[ct], 0, 0, 0);
                    acc1[ct] = __builtin_amdgcn_mfma_f32_16x16x32_bf16(A1h, Bh, acc1[ct], 0, 0, 0);
                    acc1[ct] = __builtin_amdgcn_mfma_f32_16x16x32_bf16(A1l, Bh, acc1[ct], 0, 0, 0);
                    acc1[ct] = __builtin_amdgcn_mfma_f32_16x16x32_bf16(A1h, Bl, acc1[ct], 0, 0, 0);
                }
            }
            ac0 = an0; ac1 = an1; ac2 = an2; ac3 = an3;
            __syncthreads();                         // readers done; stage(ks+1) drained
        }

        if (live) {
            const int orow = r0 + (lane >> 4) * 4;
            const int ocol = lane & 15;
#pragma unroll
            for (int ct = 0; ct < NCT; ++ct) {
                const int col = ct * 16 + ocol;
                if (col < G4) {
                    const float bias = b_ih[col] + b_hh[col];
#pragma unroll
                    for (int e = 0; e < 4; ++e) {
                        xg[(size_t)(orow + e) * G4 + col]      = acc0[ct][e] + bias;
                        xg[(size_t)(orow + 16 + e) * G4 + col] = acc1[ct][e] + bias;
                    }
                }
            }
        }
    }
}

// ---------------------------------------------------------------------------
// LSTM scan: ONE WAVE per batch. R10 showed dots/readlanes aren't the stall;
// theory: conditional prefetch loads defeat precise vmcnt tracking -> the
// compiler drains the load queue every step, exposing ~400-500 cyc of L3
// latency. Fix: UNCONDITIONAL 4 loads/step from a branchlessly-clamped
// uniform row pointer -> constant 16 outstanding, precise vmcnt(12) waits.
// ---------------------------------------------------------------------------
#define REP25(M) M(0) M(1) M(2) M(3) M(4) M(5) M(6) M(7) M(8) M(9) \
                 M(10) M(11) M(12) M(13) M(14) M(15) M(16) M(17) M(18) M(19) \
                 M(20) M(21) M(22) M(23) M(24)

__device__ __forceinline__ unsigned pk2f16(float a, float b) {
#if __has_builtin(__builtin_amdgcn_cvt_pkrtz)
    return __builtin_bit_cast(unsigned, __builtin_amdgcn_cvt_pkrtz(a, b));
#else
    f16x2 v = {(_Float16)a, (_Float16)b};
    return __builtin_bit_cast(unsigned, v);
#endif
}

#if __has_builtin(__builtin_amdgcn_fdot2)
#define FD(hu_, wu_, cc_) __builtin_amdgcn_fdot2( \
    __builtin_bit_cast(f16x2, (hu_)), __builtin_bit_cast(f16x2, (wu_)), (cc_), false)
#else
#define FD(hu_, wu_, cc_) ((cc_) \
    + (float)__builtin_bit_cast(f16x2, (hu_))[0] * (float)__builtin_bit_cast(f16x2, (wu_))[0] \
    + (float)__builtin_bit_cast(f16x2, (hu_))[1] * (float)__builtin_bit_cast(f16x2, (wu_))[1])
#endif

__global__ __launch_bounds__(64, 1) void lstm_scan(
    const float* __restrict__ xgp, const int* __restrict__ mask,
    const float* __restrict__ W_hh, const float* __restrict__ W_cls,
    const float* __restrict__ b_cls, float* __restrict__ out)
{
    const int b = blockIdx.x;
    const int l = threadIdx.x;

    int s = 0;
#pragma unroll
    for (int k = 0; k < 8; ++k) s += mask[b * S_LEN + l + 64 * k];
#pragma unroll
    for (int off = 1; off < 64; off <<= 1) s += __shfl_xor(s, off, 64);
    const int len = s;                               // >= 1

    const bool act = (l < H_DIM);
    const int  ll  = act ? l : 0;                    // clamp lane for safe loads
    const float* wr0 = W_hh + (size_t)ll * H_DIM;
    const float* wr1 = W_hh + (size_t)(50 + ll) * H_DIM;
    const float* wr2 = W_hh + (size_t)(100 + ll) * H_DIM;
    const float* wr3 = W_hh + (size_t)(150 + ll) * H_DIM;

#define WDECL(q) unsigned wi_##q, wf_##q, wg_##q, wo_##q;
    REP25(WDECL)
#undef WDECL
#define WLOAD(q) \
    wi_##q = pk2f16(wr0[2*q], wr0[2*q+1]); \
    wf_##q = pk2f16(wr1[2*q], wr1[2*q+1]); \
    wg_##q = pk2f16(wr2[2*q], wr2[2*q+1]); \
    wo_##q = pk2f16(wr3[2*q], wr3[2*q+1]);
    REP25(WLOAD)
#undef WLOAD
#define WPIN(q) asm volatile("" : "+v"(wi_##q), "+v"(wf_##q), "+v"(wg_##q), "+v"(wo_##q));
    REP25(WPIN)
#undef WPIN

    float h = 0.f, c = 0.f;
    const float* xgb = xgp + (size_t)b * S_LEN * G4;

    // prologue: fill 4 sets from rows min(0..3, len-1) -- unconditional loads
    auto ldrow = [&](int row, float& xi, float& xf, float& xq, float& xo) {
        const float* pp = xgb + (size_t)row * G4 + ll;
        xi = pp[0]; xf = pp[50]; xq = pp[100]; xo = pp[150];
    };
    float xiA,xfA,xqA,xoA, xiB,xfB,xqB,xoB;
    float xiC,xfC,xqC,xoC, xiD,xfD,xqD,xoD;
    ldrow(0,                    xiA, xfA, xqA, xoA);
    ldrow(len > 1 ? 1 : len-1,  xiB, xfB, xqB, xoB);
    ldrow(len > 2 ? 2 : len-1,  xiC, xfC, xqC, xoC);
    ldrow(len > 3 ? 3 : len-1,  xiD, xfD, xqD, xoD);

    // uniform prefetch row pointer, clamped at len-1 (branchless advance)
    const float* rowp = xgb + (size_t)(len > 4 ? 4 : len - 1) * G4;

    auto step = [&](int t, float& xi, float& xf, float& xq, float& xo) {
        // build this lane's h-pair (h[2l], h[2l+1]); broadcast via readlane
        int pa = __builtin_amdgcn_ds_bpermute(8 * l,     __float_as_int(h));
        int pb = __builtin_amdgcn_ds_bpermute(8 * l + 4, __float_as_int(h));
        unsigned hu = pk2f16(__int_as_float(pa), __int_as_float(pb));

        float ai0 = xi, af0 = xf, aq0 = xq, ao0 = xo;        // bias pre-folded
        float ai1 = 0.f, af1 = 0.f, aq1 = 0.f, ao1 = 0.f;

        // UNCONDITIONAL prefetch: always 4 loads, clamped row, safe lanes
        xi = rowp[ll]; xf = rowp[ll + 50]; xq = rowp[ll + 100]; xo = rowp[ll + 150];
        rowp += (t + 5 < len) ? G4 : 0;              // branchless clamp

#define RDECL(q) unsigned r_##q = (unsigned)__builtin_amdgcn_readlane((int)hu, q);
        REP25(RDECL)
#undef RDECL
#define DOTA(q) { ai0 = FD(r_##q, wi_##q, ai0); af0 = FD(r_##q, wf_##q, af0); \
                  aq0 = FD(r_##q, wg_##q, aq0); ao0 = FD(r_##q, wo_##q, ao0); }
#define DOTB(q) { ai1 = FD(r_##q, wi_##q, ai1); af1 = FD(r_##q, wf_##q, af1); \
                  aq1 = FD(r_##q, wg_##q, aq1); ao1 = FD(r_##q, wo_##q, ao1); }
        DOTA(0)  DOTB(1)  DOTA(2)  DOTB(3)  DOTA(4)
        DOTB(5)  DOTA(6)  DOTB(7)  DOTA(8)  DOTB(9)
        DOTA(10) DOTB(11) DOTA(12) DOTB(13) DOTA(14)
        DOTB(15) DOTA(16) DOTB(17) DOTA(18) DOTB(19)
        DOTA(20) DOTB(21) DOTA(22) DOTB(23) DOTA(24)
#undef DOTA
#undef DOTB
        float ai = ai0 + ai1, af = af0 + af1;
        float aq = aq0 + aq1, ao = ao0 + ao1;

        float ig = fsigmoid(ai), fg = fsigmoid(af);
        float gg = ftanh(aq),    og = fsigmoid(ao);
        if (act) {
            c = fg * c + ig * gg;
            h = og * ftanh(c);
        }
    };

    int t = 0;
    while (t < len) {
        step(t, xiA, xfA, xqA, xoA); ++t; if (t >= len) break;
        step(t, xiB, xfB, xqB, xoB); ++t; if (t >= len) break;
        step(t, xiC, xfC, xqC, xoC); ++t; if (t >= len) break;
        step(t, xiD, xfD, xqD, xoD); ++t;
    }

    float p0 = act ? h * W_cls[l]          : 0.f;
    float p1 = act ? h * W_cls[H_DIM + l]  : 0.f;
#pragma unroll
    for (int off = 1; off < 64; off <<= 1) {
        p0 += __shfl_xor(p0, off, 64);
        p1 += __shfl_xor(p1, off, 64);
    }
    if (l == 0) {
        out[2 * b]     = p0 + b_cls[0];
        out[2 * b + 1] = p1 + b_cls[1];
    }
}

extern "C" void kernel_launch(void* const* d_in, const int* in_sizes, int n_in,
                              void* d_out, int out_size, void* d_ws, size_t ws_size,
                              hipStream_t stream) {
    const float* x     = (const float*)d_in[0];
    const int*   mask  = (const int*)  d_in[1];
    const float* W_ih  = (const float*)d_in[2];
    const float* W_hh  = (const float*)d_in[3];
    const float* b_ih  = (const float*)d_in[4];
    const float* b_hh  = (const float*)d_in[5];
    const float* W_cls = (const float*)d_in[6];
    const float* b_cls = (const float*)d_in[7];
    float* out = (float*)d_out;
    float* xg  = (float*)d_ws;                       // 104.9 MB

    hipLaunchKernelGGL(prep_w, dim3(156), dim3(256), 0, stream, W_ih);
    hipLaunchKernelGGL(gemm_xg, dim3(512), dim3(256), 0, stream, x, mask, b_ih, b_hh, xg);
    hipLaunchKernelGGL(lstm_scan, dim3(256), dim3(64), 0, stream,
                       xg, mask, W_hh, W_cls, b_cls, out);
}

// Round 12
// 330.576 us; speedup vs baseline: 1.0655x; 1.0655x over previous
//
#include <hip/hip_runtime.h>
#include <math.h>

#define S_LEN 512
#define D_IN  768
#define H_DIM 50
#define G4    200
#define NCT   13
#define BROWS 128
#define NTILES 1024      // (256*512)/128
#define KSTEPS 24        // 768/32
#define FR_KS  13312     // ushorts per K-step of frag-packed W (26,624 B)

typedef float   f32x4 __attribute__((ext_vector_type(4)));
typedef short   s16x8 __attribute__((ext_vector_type(8)));
typedef _Float16 f16x2 __attribute__((ext_vector_type(2)));

__device__ ushort g_Wf[KSTEPS * FR_KS];   // [ks][ct][half][lane][8]
__device__ int    g_counter;

#define LOG2E 1.44269504f

__device__ __forceinline__ float fexp2(float x) {
#if __has_builtin(__builtin_amdgcn_exp2f)
    return __builtin_amdgcn_exp2f(x);
#else
    return exp2f(x);
#endif
}
__device__ __forceinline__ float frcp(float x) {
#if __has_builtin(__builtin_amdgcn_rcpf)
    return __builtin_amdgcn_rcpf(x);
#else
    return 1.0f / x;
#endif
}
__device__ __forceinline__ float fsigmoid(float x) {
    return frcp(1.0f + fexp2(-LOG2E * x));
}
// tanh(x) = 2*sigmoid(2x) - 1 : mul, exp, add, rcp, fma — 5 instrs, monotone,
// correct saturation at +/-inf. Shorter serial chain than the (1-e)/(1+e) form.
__device__ __forceinline__ float ftanh2(float x) {
    return __builtin_fmaf(2.0f, frcp(1.0f + fexp2(-2.0f * LOG2E * x)), -1.0f);
}

// ---------------------------------------------------------------------------
// prep: pack W_ih into MFMA-frag-linear bf16 hi/lo: g_Wf[ks][ct][half][lane][8]
// ---------------------------------------------------------------------------
__global__ void prep_w(const float* __restrict__ W) {
    int f = blockIdx.x * 256 + threadIdx.x;          // frag id
    if (f == 0) g_counter = 0;
    if (f >= KSTEPS * 26 * 64) return;               // 39936 frags
    const int l  = f & 63;
    const int g  = (f >> 6) % 26;
    const int ks = (f >> 6) / 26;
    const int ct = g >> 1, hf = g & 1;
    const int n  = ct * 16 + (l & 15);
    const int k0 = ks * 32 + (l >> 4) * 8;
    ushort v[8] __attribute__((aligned(16)));
#pragma unroll
    for (int j = 0; j < 8; ++j) v[j] = 0;
    if (n < G4) {
        const float* wp = &W[(size_t)n * D_IN + k0];
#pragma unroll
        for (int j = 0; j < 8; ++j) {
            float xv = wp[j];
            unsigned u = __float_as_uint(xv);
            if (hf == 0) v[j] = (ushort)(u >> 16);
            else {
                float d = xv - __uint_as_float(u & 0xffff0000u);
                v[j] = (ushort)(__float_as_uint(d) >> 16);
            }
        }
    }
    *(uint4*)&g_Wf[(size_t)f * 8] = *(const uint4*)v;
}

__device__ __forceinline__ void pack2(float f0, float f1, unsigned& h, unsigned& l) {
    unsigned u0 = __float_as_uint(f0), u1 = __float_as_uint(f1);
    h = (u0 >> 16) | (u1 & 0xffff0000u);
    float d0 = f0 - __uint_as_float(u0 & 0xffff0000u);
    float d1 = f1 - __uint_as_float(u1 & 0xffff0000u);
    l = (__float_as_uint(d0) >> 16) | (__float_as_uint(d1) & 0xffff0000u);
}

// async-stage one K-step of packed W into LDS (26,624 B).
__device__ __forceinline__ void stage_b(int ks, ushort* dst, int wv, int lane) {
    const ushort* gb = g_Wf + (size_t)ks * FR_KS;
#pragma unroll
    for (int i = 0; i < 7; ++i) {
        const int c0 = i * 2048 + wv * 512;          // ushort units
        if (c0 < FR_KS) {
#if __has_builtin(__builtin_amdgcn_global_load_lds)
            __builtin_amdgcn_global_load_lds(
                (const __attribute__((address_space(1))) unsigned int*)(gb + c0 + lane * 8),
                (__attribute__((address_space(3))) unsigned int*)(dst + c0),
                16, 0, 0);
#else
            *(uint4*)(dst + c0 + (size_t)lane * 8) = *(const uint4*)(gb + c0 + (size_t)lane * 8);
#endif
        }
    }
}

// ---------------------------------------------------------------------------
// xg = x @ W_ih^T (+ bias), split-bf16 MFMA. Epilogue now writes the
// TRANSPOSED per-row layout xg[b][t][j*4+g] (j = h-dim, g = gate) so the
// scan reads one float4 per lane per step.
// ---------------------------------------------------------------------------
__global__ __launch_bounds__(256, 2) void gemm_xg(
    const float* __restrict__ x, const int* __restrict__ mask,
    const float* __restrict__ b_ih, const float* __restrict__ b_hh,
    float* __restrict__ xg)
{
    __shared__ ushort Bs[2][FR_KS];                  // 53,248 B
    __shared__ int tile_sh;
    const int tid  = threadIdx.x;
    const int wv   = tid >> 6;
    const int lane = tid & 63;
    const int lr   = lane & 15;
    const int kch  = (lane >> 4) * 8;

    for (;;) {
        if (tid == 0) tile_sh = atomicAdd(&g_counter, 1);
        __syncthreads();
        const int tile = tile_sh;
        __syncthreads();
        if (tile >= NTILES) return;

        const int row0 = tile * BROWS;
        const int b    = row0 >> 9;
        const int t0   = row0 & (S_LEN - 1);
        if (mask[b * S_LEN + t0] == 0) continue;     // whole tile past length[b]
        const bool live = mask[b * S_LEN + t0 + wv * 32] != 0;

        const int r0 = row0 + wv * 32;
        const float* xr0 = x + (size_t)(r0 + lr) * D_IN;
        const float* xr1 = xr0 + (size_t)16 * D_IN;

        f32x4 acc0[NCT], acc1[NCT];
#pragma unroll
        for (int i = 0; i < NCT; ++i) {
            acc0[i] = (f32x4){0.f, 0.f, 0.f, 0.f};
            acc1[i] = (f32x4){0.f, 0.f, 0.f, 0.f};
        }
        float4 ac0 = {0,0,0,0}, ac1 = {0,0,0,0}, ac2 = {0,0,0,0}, ac3 = {0,0,0,0};
        float4 an0 = {0,0,0,0}, an1 = {0,0,0,0}, an2 = {0,0,0,0}, an3 = {0,0,0,0};

        stage_b(0, Bs[0], wv, lane);
        if (live) {
            ac0 = *(const float4*)(xr0 + kch);
            ac1 = *(const float4*)(xr0 + kch + 4);
            ac2 = *(const float4*)(xr1 + kch);
            ac3 = *(const float4*)(xr1 + kch + 4);
        }
        __syncthreads();                             // Bs[0] staged & drained

        for (int ks = 0; ks < KSTEPS; ++ks) {
            if (ks < KSTEPS - 1) {
                stage_b(ks + 1, Bs[(ks + 1) & 1], wv, lane);
                if (live) {
                    const int k1 = (ks + 1) * 32 + kch;
                    an0 = *(const float4*)(xr0 + k1);
                    an1 = *(const float4*)(xr0 + k1 + 4);
                    an2 = *(const float4*)(xr1 + k1);
                    an3 = *(const float4*)(xr1 + k1 + 4);
                }
            }
            if (live) {
                uint4 h0, l0, h1, l1;
                pack2(ac0.x, ac0.y, h0.x, l0.x); pack2(ac0.z, ac0.w, h0.y, l0.y);
                pack2(ac1.x, ac1.y, h0.z, l0.z); pack2(ac1.z, ac1.w, h0.w, l0.w);
                pack2(ac2.x, ac2.y, h1.x, l1.x); pack2(ac2.z, ac2.w, h1.y, l1.y);
                pack2(ac3.x, ac3.y, h1.z, l1.z); pack2(ac3.z, ac3.w, h1.w, l1.w);
                s16x8 A0h = *(s16x8*)&h0, A0l = *(s16x8*)&l0;
                s16x8 A1h = *(s16x8*)&h1, A1l = *(s16x8*)&l1;
                const ushort* bp = &Bs[ks & 1][lane * 8];
#pragma unroll
                for (int ct = 0; ct < NCT; ++ct) {
                    s16x8 Bh = *(const s16x8*)(bp + ct * 1024);
                    s16x8 Bl = *(const s16x8*)(bp + ct * 1024 + 512);
                    acc0[ct] = __builtin_amdgcn_mfma_f32_16x16x32_bf16(A0h, Bh, acc0[ct], 0, 0, 0);
                    acc0[ct] = __builtin_amdgcn_mfma_f32_16x16x32_bf16(A0l, Bh, acc0[ct], 0, 0, 0);
                    acc0[ct] = __builtin_amdgcn_mfma_f32_16x16x32_bf16(A0h, Bl, acc0[ct], 0, 0, 0);
                    acc1[ct] = __builtin_amdgcn_mfma_f32_16x16x32_bf16(A1h, Bh, acc1[ct], 0, 0, 0);
                    acc1[ct] = __builtin_amdgcn_mfma_f32_16x16x32_bf16(A1l, Bh, acc1[ct], 0, 0, 0);
                    acc1[ct] = __builtin_amdgcn_mfma_f32_16x16x32_bf16(A1h, Bl, acc1[ct], 0, 0, 0);
                }
            }
            ac0 = an0; ac1 = an1; ac2 = an2; ac3 = an3;
            __syncthreads();                         // readers done; stage(ks+1) drained
        }

        if (live) {
            const int orow = r0 + (lane >> 4) * 4;
            const int ocol = lane & 15;
#pragma unroll
            for (int ct = 0; ct < NCT; ++ct) {
                const int n = ct * 16 + ocol;
                if (n < G4) {
                    const int g = n / 50, j = n - g * 50;
                    const int off = j * 4 + g;       // [j][gate] layout
                    const float bias = b_ih[n] + b_hh[n];
#pragma unroll
                    for (int e = 0; e < 4; ++e) {
                        xg[(size_t)(orow + e) * G4 + off]      = acc0[ct][e] + bias;
                        xg[(size_t)(orow + 16 + e) * G4 + off] = acc1[ct][e] + bias;
                    }
                }
            }
        }
    }
}

// ---------------------------------------------------------------------------
// LSTM scan: ONE WAVE per batch. R12: serial-chain diet.
//  - h-pair packing via DPP quad_perm xor-1 swap (no ds_bpermute / LDS).
//  - xg[t][j*4+g] layout: ONE dwordx4 load per step, issued after the dots
//    (sched_barrier-pinned) so precise vmcnt waits keep it 4 steps deep.
//  - tanh = 2*sigmoid(2x)-1 (5 instrs).
// ---------------------------------------------------------------------------
#define REP25(M) M(0) M(1) M(2) M(3) M(4) M(5) M(6) M(7) M(8) M(9) \
                 M(10) M(11) M(12) M(13) M(14) M(15) M(16) M(17) M(18) M(19) \
                 M(20) M(21) M(22) M(23) M(24)

__device__ __forceinline__ unsigned pk2f16(float a, float b) {
#if __has_builtin(__builtin_amdgcn_cvt_pkrtz)
    return __builtin_bit_cast(unsigned, __builtin_amdgcn_cvt_pkrtz(a, b));
#else
    f16x2 v = {(_Float16)a, (_Float16)b};
    return __builtin_bit_cast(unsigned, v);
#endif
}

#if __has_builtin(__builtin_amdgcn_fdot2)
#define FD(hu_, wu_, cc_) __builtin_amdgcn_fdot2( \
    __builtin_bit_cast(f16x2, (hu_)), __builtin_bit_cast(f16x2, (wu_)), (cc_), false)
#else
#define FD(hu_, wu_, cc_) ((cc_) \
    + (float)__builtin_bit_cast(f16x2, (hu_))[0] * (float)__builtin_bit_cast(f16x2, (wu_))[0] \
    + (float)__builtin_bit_cast(f16x2, (hu_))[1] * (float)__builtin_bit_cast(f16x2, (wu_))[1])
#endif

__device__ __forceinline__ void sbar0() {
#if __has_builtin(__builtin_amdgcn_sched_barrier)
    __builtin_amdgcn_sched_barrier(0);
#endif
}

__global__ __launch_bounds__(64, 1) void lstm_scan(
    const float* __restrict__ xgp, const int* __restrict__ mask,
    const float* __restrict__ W_hh, const float* __restrict__ W_cls,
    const float* __restrict__ b_cls, float* __restrict__ out)
{
    const int b = blockIdx.x;
    const int l = threadIdx.x;

    int s = 0;
#pragma unroll
    for (int k = 0; k < 8; ++k) s += mask[b * S_LEN + l + 64 * k];
#pragma unroll
    for (int off = 1; off < 64; off <<= 1) s += __shfl_xor(s, off, 64);
    const int len = s;                               // >= 1

    const bool act = (l < H_DIM);
    const int  ll  = act ? l : 0;                    // clamp lane for safe loads
    const float* wr0 = W_hh + (size_t)ll * H_DIM;
    const float* wr1 = W_hh + (size_t)(50 + ll) * H_DIM;
    const float* wr2 = W_hh + (size_t)(100 + ll) * H_DIM;
    const float* wr3 = W_hh + (size_t)(150 + ll) * H_DIM;

#define WDECL(q) unsigned wi_##q, wf_##q, wg_##q, wo_##q;
    REP25(WDECL)
#undef WDECL
#define WLOAD(q) \
    wi_##q = pk2f16(wr0[2*q], wr0[2*q+1]); \
    wf_##q = pk2f16(wr1[2*q], wr1[2*q+1]); \
    wg_##q = pk2f16(wr2[2*q], wr2[2*q+1]); \
    wo_##q = pk2f16(wr3[2*q], wr3[2*q+1]);
    REP25(WLOAD)
#undef WLOAD
#define WPIN(q) asm volatile("" : "+v"(wi_##q), "+v"(wf_##q), "+v"(wg_##q), "+v"(wo_##q));
    REP25(WPIN)
#undef WPIN

    float h = 0.f, c = 0.f;
    const float* xgb = xgp + (size_t)b * S_LEN * G4;

    // 4-deep prologue, clamped rows, one float4 per set
    auto ldrow = [&](int row) -> float4 {
        return *(const float4*)(xgb + (size_t)row * G4 + ll * 4);
    };
    float4 vA = ldrow(0);
    float4 vB = ldrow(len > 1 ? 1 : len - 1);
    float4 vC = ldrow(len > 2 ? 2 : len - 1);
    float4 vD = ldrow(len > 3 ? 3 : len - 1);
    const float* rowp = xgb + (size_t)(len > 4 ? 4 : len - 1) * G4 + ll * 4;

    auto step = [&](int t, float4& v) {
        // pack this lane's h-pair: DPP xor-1 swap (quad_perm [1,0,3,2]) + cvt
#if __has_builtin(__builtin_amdgcn_mov_dpp)
        int hsw = __builtin_amdgcn_mov_dpp(__float_as_int(h), 0xB1, 0xF, 0xF, true);
#else
        int hsw = __float_as_int(__shfl_xor(h, 1, 64));
#endif
        unsigned hu = pk2f16(h, __int_as_float(hsw));
        // lane 2q now holds (h[2q], h[2q+1]) packed -> broadcast even lanes

        float ai0 = v.x, af0 = v.y, aq0 = v.z, ao0 = v.w;   // i,f,g,o (bias folded)
        float ai1 = 0.f, af1 = 0.f, aq1 = 0.f, ao1 = 0.f;

#define RDECL(q) unsigned r_##q = (unsigned)__builtin_amdgcn_readlane((int)hu, 2*q);
        REP25(RDECL)
#undef RDECL
#define DOTA(q) { ai0 = FD(r_##q, wi_##q, ai0); af0 = FD(r_##q, wf_##q, af0); \
                  aq0 = FD(r_##q, wg_##q, aq0); ao0 = FD(r_##q, wo_##q, ao0); }
#define DOTB(q) { ai1 = FD(r_##q, wi_##q, ai1); af1 = FD(r_##q, wf_##q, af1); \
                  aq1 = FD(r_##q, wg_##q, aq1); ao1 = FD(r_##q, wo_##q, ao1); }
        DOTA(0)  DOTB(1)  DOTA(2)  DOTB(3)  DOTA(4)
        DOTB(5)  DOTA(6)  DOTB(7)  DOTA(8)  DOTB(9)
        DOTA(10) DOTB(11) DOTA(12) DOTB(13) DOTA(14)
        DOTB(15) DOTA(16) DOTB(17) DOTA(18) DOTB(19)
        DOTA(20) DOTB(21) DOTA(22) DOTB(23) DOTA(24)
#undef DOTA
#undef DOTB
        float ai = ai0 + ai1, af = af0 + af1;
        float aq = aq0 + aq1, ao = ao0 + ao1;

        // prefetch t+4 AFTER the dots (pinned) -> 4-step-deep vmcnt pipeline
        sbar0();
        v = *(const float4*)rowp;
        rowp += (t + 5 < len) ? G4 : 0;              // branchless clamp
        sbar0();

        float ig = fsigmoid(ai), fg = fsigmoid(af);
        float gg = ftanh2(aq),   og = fsigmoid(ao);
        c = fg * c + ig * gg;                        // lanes >=50: harmless finite
        h = og * ftanh2(c);
    };

    int t = 0;
    while (t < len) {
        step(t, vA); ++t; if (t >= len) break;
        step(t, vB); ++t; if (t >= len) break;
        step(t, vC); ++t; if (t >= len) break;
        step(t, vD); ++t;
    }

    float p0 = act ? h * W_cls[l]          : 0.f;
    float p1 = act ? h * W_cls[H_DIM + l]  : 0.f;
#pragma unroll
    for (int off = 1; off < 64; off <<= 1) {
        p0 += __shfl_xor(p0, off, 64);
        p1 += __shfl_xor(p1, off, 64);
    }
    if (l == 0) {
        out[2 * b]     = p0 + b_cls[0];
        out[2 * b + 1] = p1 + b_cls[1];
    }
}

extern "C" void kernel_launch(void* const* d_in, const int* in_sizes, int n_in,
                              void* d_out, int out_size, void* d_ws, size_t ws_size,
                              hipStream_t stream) {
    const float* x     = (const float*)d_in[0];
    const int*   mask  = (const int*)  d_in[1];
    const float* W_ih  = (const float*)d_in[2];
    const float* W_hh  = (const float*)d_in[3];
    const float* b_ih  = (const float*)d_in[4];
    const float* b_hh  = (const float*)d_in[5];
    const float* W_cls = (const float*)d_in[6];
    const float* b_cls = (const float*)d_in[7];
    float* out = (float*)d_out;
    float* xg  = (float*)d_ws;                       // 104.9 MB

    hipLaunchKernelGGL(prep_w, dim3(156), dim3(256), 0, stream, W_ih);
    hipLaunchKernelGGL(gemm_xg, dim3(512), dim3(256), 0, stream, x, mask, b_ih, b_hh, xg);
    hipLaunchKernelGGL(lstm_scan, dim3(256), dim3(64), 0, stream,
                       xg, mask, W_hh, W_cls, b_cls, out);
}

// Round 13
// 323.231 us; speedup vs baseline: 1.0897x; 1.0227x over previous
//
#include <hip/hip_runtime.h>
#include <math.h>

#define S_LEN 512
#define D_IN  768
#define H_DIM 50
#define G4    200
#define NCT   13
#define BROWS 256
#define NTILES 512       // (256*512)/256
#define KSTEPS 24        // 768/32
#define FR_KS  6656      // ushorts per K-step: 13 ct x 64 lanes x 8 (13,312 B)

typedef float   f32x4 __attribute__((ext_vector_type(4)));
typedef short   s16x8 __attribute__((ext_vector_type(8)));
typedef _Float16 f16x2 __attribute__((ext_vector_type(2)));

__device__ ushort g_Wf[KSTEPS * FR_KS];   // [ks][ct][lane][8], RNE bf16
__device__ int    g_counter;

#define LOG2E 1.44269504f

__device__ __forceinline__ float fexp2(float x) {
#if __has_builtin(__builtin_amdgcn_exp2f)
    return __builtin_amdgcn_exp2f(x);
#else
    return exp2f(x);
#endif
}
__device__ __forceinline__ float frcp(float x) {
#if __has_builtin(__builtin_amdgcn_rcpf)
    return __builtin_amdgcn_rcpf(x);
#else
    return 1.0f / x;
#endif
}
__device__ __forceinline__ float fsigmoid(float x) {
    return frcp(1.0f + fexp2(-LOG2E * x));
}
__device__ __forceinline__ float ftanh2(float x) {
    return __builtin_fmaf(2.0f, frcp(1.0f + fexp2(-2.0f * LOG2E * x)), -1.0f);
}

// ---------------------------------------------------------------------------
// prep: W_ih -> frag-linear RNE-rounded bf16 g_Wf[ks][ct][lane][8].
// 2-term split (AhBh + AlBh) corrects A to 2^-16; B error is RNE bf16
// (unbiased +/-0.5ulp), predicted xg err sigma ~1.2e-3.
// ---------------------------------------------------------------------------
__global__ void prep_w(const float* __restrict__ W) {
    int f = blockIdx.x * 256 + threadIdx.x;          // frag id [ks][ct][lane]
    if (f == 0) g_counter = 0;
    if (f >= KSTEPS * NCT * 64) return;              // 19,968
    const int l  = f & 63;
    const int ct = (f >> 6) % NCT;
    const int ks = (f >> 6) / NCT;
    const int n  = ct * 16 + (l & 15);
    const int k0 = ks * 32 + (l >> 4) * 8;
    ushort v[8] __attribute__((aligned(16)));
#pragma unroll
    for (int j = 0; j < 8; ++j) v[j] = 0;
    if (n < G4) {
        const float* wp = &W[(size_t)n * D_IN + k0];
#pragma unroll
        for (int j = 0; j < 8; ++j) {
            unsigned u = __float_as_uint(wp[j]);
            v[j] = (ushort)((u + 0x7FFFu + ((u >> 16) & 1u)) >> 16);  // RNE bf16
        }
    }
    *(uint4*)&g_Wf[(size_t)f * 8] = *(const uint4*)v;
}

__device__ __forceinline__ void pack2(float f0, float f1, unsigned& h, unsigned& l) {
    unsigned u0 = __float_as_uint(f0), u1 = __float_as_uint(f1);
    h = (u0 >> 16) | (u1 & 0xffff0000u);
    float d0 = f0 - __uint_as_float(u0 & 0xffff0000u);
    float d1 = f1 - __uint_as_float(u1 & 0xffff0000u);
    l = (__float_as_uint(d0) >> 16) | (__float_as_uint(d1) & 0xffff0000u);
}

// async-stage one K-step of Bh into LDS (13,312 B); 8 waves cover 13 chunks.
__device__ __forceinline__ void stage_b(int ks, ushort* dst, int wv, int lane) {
    const ushort* gb = g_Wf + (size_t)ks * FR_KS;
#pragma unroll
    for (int i = 0; i < 2; ++i) {
        const int chunk = i * 8 + wv;
        if (chunk < 13) {
            const int c0 = chunk * 512;              // ushort units (1 KB)
#if __has_builtin(__builtin_amdgcn_global_load_lds)
            __builtin_amdgcn_global_load_lds(
                (const __attribute__((address_space(1))) unsigned int*)(gb + c0 + lane * 8),
                (__attribute__((address_space(3))) unsigned int*)(dst + c0),
                16, 0, 0);
#else
            *(uint4*)(dst + c0 + (size_t)lane * 8) = *(const uint4*)(gb + c0 + (size_t)lane * 8);
#endif
        }
    }
}

// ---------------------------------------------------------------------------
// xg = x @ W_ih^T (+ bias), 2-term split-bf16 MFMA (AhBh + AlBh).
// 256-row tiles, 8 waves/block (512 thr), grid 256: per-CU per-iter VMEM
// instrs 116 -> 77, B staged once per 256 rows, LDS dbuf 26.6 KB.
// Epilogue writes the scan's [t][j*4+g] layout.
// ---------------------------------------------------------------------------
__global__ __launch_bounds__(512, 2) void gemm_xg(
    const float* __restrict__ x, const int* __restrict__ mask,
    const float* __restrict__ b_ih, const float* __restrict__ b_hh,
    float* __restrict__ xg)
{
    __shared__ ushort Bs[2][FR_KS];                  // 26,624 B
    __shared__ int tile_sh;
    const int tid  = threadIdx.x;
    const int wv   = tid >> 6;                       // 0..7
    const int lane = tid & 63;
    const int lr   = lane & 15;
    const int kch  = (lane >> 4) * 8;

    for (;;) {
        if (tid == 0) tile_sh = atomicAdd(&g_counter, 1);
        __syncthreads();
        const int tile = tile_sh;
        __syncthreads();
        if (tile >= NTILES) return;

        const int row0 = tile * BROWS;
        const int b    = row0 >> 9;
        const int t0   = row0 & (S_LEN - 1);         // 0 or 256
        if (mask[b * S_LEN + t0] == 0) continue;     // whole tile past length[b]
        const bool live = mask[b * S_LEN + t0 + wv * 32] != 0;

        const int r0 = row0 + wv * 32;
        const float* xr0 = x + (size_t)(r0 + lr) * D_IN;
        const float* xr1 = xr0 + (size_t)16 * D_IN;

        f32x4 acc0[NCT], acc1[NCT];
#pragma unroll
        for (int i = 0; i < NCT; ++i) {
            acc0[i] = (f32x4){0.f, 0.f, 0.f, 0.f};
            acc1[i] = (f32x4){0.f, 0.f, 0.f, 0.f};
        }
        float4 ac0 = {0,0,0,0}, ac1 = {0,0,0,0}, ac2 = {0,0,0,0}, ac3 = {0,0,0,0};
        float4 an0 = {0,0,0,0}, an1 = {0,0,0,0}, an2 = {0,0,0,0}, an3 = {0,0,0,0};

        stage_b(0, Bs[0], wv, lane);
        if (live) {
            ac0 = *(const float4*)(xr0 + kch);
            ac1 = *(const float4*)(xr0 + kch + 4);
            ac2 = *(const float4*)(xr1 + kch);
            ac3 = *(const float4*)(xr1 + kch + 4);
        }
        __syncthreads();                             // Bs[0] staged & drained

        for (int ks = 0; ks < KSTEPS; ++ks) {
            if (ks < KSTEPS - 1) {
                stage_b(ks + 1, Bs[(ks + 1) & 1], wv, lane);
                if (live) {
                    const int k1 = (ks + 1) * 32 + kch;
                    an0 = *(const float4*)(xr0 + k1);
                    an1 = *(const float4*)(xr0 + k1 + 4);
                    an2 = *(const float4*)(xr1 + k1);
                    an3 = *(const float4*)(xr1 + k1 + 4);
                }
            }
            if (live) {
                uint4 h0, l0, h1, l1;
                pack2(ac0.x, ac0.y, h0.x, l0.x); pack2(ac0.z, ac0.w, h0.y, l0.y);
                pack2(ac1.x, ac1.y, h0.z, l0.z); pack2(ac1.z, ac1.w, h0.w, l0.w);
                pack2(ac2.x, ac2.y, h1.x, l1.x); pack2(ac2.z, ac2.w, h1.y, l1.y);
                pack2(ac3.x, ac3.y, h1.z, l1.z); pack2(ac3.z, ac3.w, h1.w, l1.w);
                s16x8 A0h = *(s16x8*)&h0, A0l = *(s16x8*)&l0;
                s16x8 A1h = *(s16x8*)&h1, A1l = *(s16x8*)&l1;
                const ushort* bp = &Bs[ks & 1][lane * 8];
#pragma unroll
                for (int ct = 0; ct < NCT; ++ct) {
                    s16x8 Bh = *(const s16x8*)(bp + ct * 512);
                    acc0[ct] = __builtin_amdgcn_mfma_f32_16x16x32_bf16(A0h, Bh, acc0[ct], 0, 0, 0);
                    acc0[ct] = __builtin_amdgcn_mfma_f32_16x16x32_bf16(A0l, Bh, acc0[ct], 0, 0, 0);
                    acc1[ct] = __builtin_amdgcn_mfma_f32_16x16x32_bf16(A1h, Bh, acc1[ct], 0, 0, 0);
                    acc1[ct] = __builtin_amdgcn_mfma_f32_16x16x32_bf16(A1l, Bh, acc1[ct], 0, 0, 0);
                }
            }
            ac0 = an0; ac1 = an1; ac2 = an2; ac3 = an3;
            __syncthreads();                         // readers done; stage(ks+1) drained
        }

        if (live) {
            const int orow = r0 + (lane >> 4) * 4;
            const int ocol = lane & 15;
#pragma unroll
            for (int ct = 0; ct < NCT; ++ct) {
                const int n = ct * 16 + ocol;
                if (n < G4) {
                    const int g = n / 50, j = n - g * 50;
                    const int off = j * 4 + g;       // [j][gate] layout
                    const float bias = b_ih[n] + b_hh[n];
#pragma unroll
                    for (int e = 0; e < 4; ++e) {
                        xg[(size_t)(orow + e) * G4 + off]      = acc0[ct][e] + bias;
                        xg[(size_t)(orow + 16 + e) * G4 + off] = acc1[ct][e] + bias;
                    }
                }
            }
        }
    }
}

// ---------------------------------------------------------------------------
// LSTM scan: unchanged from R12 (near its single-wave latency floor).
// ---------------------------------------------------------------------------
#define REP25(M) M(0) M(1) M(2) M(3) M(4) M(5) M(6) M(7) M(8) M(9) \
                 M(10) M(11) M(12) M(13) M(14) M(15) M(16) M(17) M(18) M(19) \
                 M(20) M(21) M(22) M(23) M(24)

__device__ __forceinline__ unsigned pk2f16(float a, float b) {
#if __has_builtin(__builtin_amdgcn_cvt_pkrtz)
    return __builtin_bit_cast(unsigned, __builtin_amdgcn_cvt_pkrtz(a, b));
#else
    f16x2 v = {(_Float16)a, (_Float16)b};
    return __builtin_bit_cast(unsigned, v);
#endif
}

#if __has_builtin(__builtin_amdgcn_fdot2)
#define FD(hu_, wu_, cc_) __builtin_amdgcn_fdot2( \
    __builtin_bit_cast(f16x2, (hu_)), __builtin_bit_cast(f16x2, (wu_)), (cc_), false)
#else
#define FD(hu_, wu_, cc_) ((cc_) \
    + (float)__builtin_bit_cast(f16x2, (hu_))[0] * (float)__builtin_bit_cast(f16x2, (wu_))[0] \
    + (float)__builtin_bit_cast(f16x2, (hu_))[1] * (float)__builtin_bit_cast(f16x2, (wu_))[1])
#endif

__device__ __forceinline__ void sbar0() {
#if __has_builtin(__builtin_amdgcn_sched_barrier)
    __builtin_amdgcn_sched_barrier(0);
#endif
}

__global__ __launch_bounds__(64, 1) void lstm_scan(
    const float* __restrict__ xgp, const int* __restrict__ mask,
    const float* __restrict__ W_hh, const float* __restrict__ W_cls,
    const float* __restrict__ b_cls, float* __restrict__ out)
{
    const int b = blockIdx.x;
    const int l = threadIdx.x;

    int s = 0;
#pragma unroll
    for (int k = 0; k < 8; ++k) s += mask[b * S_LEN + l + 64 * k];
#pragma unroll
    for (int off = 1; off < 64; off <<= 1) s += __shfl_xor(s, off, 64);
    const int len = s;                               // >= 1

    const bool act = (l < H_DIM);
    const int  ll  = act ? l : 0;                    // clamp lane for safe loads
    const float* wr0 = W_hh + (size_t)ll * H_DIM;
    const float* wr1 = W_hh + (size_t)(50 + ll) * H_DIM;
    const float* wr2 = W_hh + (size_t)(100 + ll) * H_DIM;
    const float* wr3 = W_hh + (size_t)(150 + ll) * H_DIM;

#define WDECL(q) unsigned wi_##q, wf_##q, wg_##q, wo_##q;
    REP25(WDECL)
#undef WDECL
#define WLOAD(q) \
    wi_##q = pk2f16(wr0[2*q], wr0[2*q+1]); \
    wf_##q = pk2f16(wr1[2*q], wr1[2*q+1]); \
    wg_##q = pk2f16(wr2[2*q], wr2[2*q+1]); \
    wo_##q = pk2f16(wr3[2*q], wr3[2*q+1]);
    REP25(WLOAD)
#undef WLOAD
#define WPIN(q) asm volatile("" : "+v"(wi_##q), "+v"(wf_##q), "+v"(wg_##q), "+v"(wo_##q));
    REP25(WPIN)
#undef WPIN

    float h = 0.f, c = 0.f;
    const float* xgb = xgp + (size_t)b * S_LEN * G4;

    auto ldrow = [&](int row) -> float4 {
        return *(const float4*)(xgb + (size_t)row * G4 + ll * 4);
    };
    float4 vA = ldrow(0);
    float4 vB = ldrow(len > 1 ? 1 : len - 1);
    float4 vC = ldrow(len > 2 ? 2 : len - 1);
    float4 vD = ldrow(len > 3 ? 3 : len - 1);
    const float* rowp = xgb + (size_t)(len > 4 ? 4 : len - 1) * G4 + ll * 4;

    auto step = [&](int t, float4& v) {
#if __has_builtin(__builtin_amdgcn_mov_dpp)
        int hsw = __builtin_amdgcn_mov_dpp(__float_as_int(h), 0xB1, 0xF, 0xF, true);
#else
        int hsw = __float_as_int(__shfl_xor(h, 1, 64));
#endif
        unsigned hu = pk2f16(h, __int_as_float(hsw));

        float ai0 = v.x, af0 = v.y, aq0 = v.z, ao0 = v.w;
        float ai1 = 0.f, af1 = 0.f, aq1 = 0.f, ao1 = 0.f;

#define RDECL(q) unsigned r_##q = (unsigned)__builtin_amdgcn_readlane((int)hu, 2*q);
        REP25(RDECL)
#undef RDECL
#define DOTA(q) { ai0 = FD(r_##q, wi_##q, ai0); af0 = FD(r_##q, wf_##q, af0); \
                  aq0 = FD(r_##q, wg_##q, aq0); ao0 = FD(r_##q, wo_##q, ao0); }
#define DOTB(q) { ai1 = FD(r_##q, wi_##q, ai1); af1 = FD(r_##q, wf_##q, af1); \
                  aq1 = FD(r_##q, wg_##q, aq1); ao1 = FD(r_##q, wo_##q, ao1); }
        DOTA(0)  DOTB(1)  DOTA(2)  DOTB(3)  DOTA(4)
        DOTB(5)  DOTA(6)  DOTB(7)  DOTA(8)  DOTB(9)
        DOTA(10) DOTB(11) DOTA(12) DOTB(13) DOTA(14)
        DOTB(15) DOTA(16) DOTB(17) DOTA(18) DOTB(19)
        DOTA(20) DOTB(21) DOTA(22) DOTB(23) DOTA(24)
#undef DOTA
#undef DOTB
        float ai = ai0 + ai1, af = af0 + af1;
        float aq = aq0 + aq1, ao = ao0 + ao1;

        sbar0();
        v = *(const float4*)rowp;
        rowp += (t + 5 < len) ? G4 : 0;              // branchless clamp
        sbar0();

        float ig = fsigmoid(ai), fg = fsigmoid(af);
        float gg = ftanh2(aq),   og = fsigmoid(ao);
        c = fg * c + ig * gg;
        h = og * ftanh2(c);
    };

    int t = 0;
    while (t < len) {
        step(t, vA); ++t; if (t >= len) break;
        step(t, vB); ++t; if (t >= len) break;
        step(t, vC); ++t; if (t >= len) break;
        step(t, vD); ++t;
    }

    float p0 = act ? h * W_cls[l]          : 0.f;
    float p1 = act ? h * W_cls[H_DIM + l]  : 0.f;
#pragma unroll
    for (int off = 1; off < 64; off <<= 1) {
        p0 += __shfl_xor(p0, off, 64);
        p1 += __shfl_xor(p1, off, 64);
    }
    if (l == 0) {
        out[2 * b]     = p0 + b_cls[0];
        out[2 * b + 1] = p1 + b_cls[1];
    }
}

extern "C" void kernel_launch(void* const* d_in, const int* in_sizes, int n_in,
                              void* d_out, int out_size, void* d_ws, size_t ws_size,
                              hipStream_t stream) {
    const float* x     = (const float*)d_in[0];
    const int*   mask  = (const int*)  d_in[1];
    const float* W_ih  = (const float*)d_in[2];
    const float* W_hh  = (const float*)d_in[3];
    const float* b_ih  = (const float*)d_in[4];
    const float* b_hh  = (const float*)d_in[5];
    const float* W_cls = (const float*)d_in[6];
    const float* b_cls = (const float*)d_in[7];
    float* out = (float*)d_out;
    float* xg  = (float*)d_ws;                       // 104.9 MB

    hipLaunchKernelGGL(prep_w, dim3(78), dim3(256), 0, stream, W_ih);
    hipLaunchKernelGGL(gemm_xg, dim3(256), dim3(512), 0, stream, x, mask, b_ih, b_hh, xg);
    hipLaunchKernelGGL(lstm_scan, dim3(256), dim3(64), 0, stream,
                       xg, mask, W_hh, W_cls, b_cls, out);
}

// Round 14
// 289.601 us; speedup vs baseline: 1.2163x; 1.1161x over previous
//
#include <hip/hip_runtime.h>
#include <math.h>

#define S_LEN 512
#define D_IN  768
#define H_DIM 50
#define G4    200
#define NCT   13
#define KSTEPS 24        // 768/32
#define FR_KS  6656      // ushorts per K-step: 13 ct x 64 lanes x 8
#define CHROWS 32        // rows per chunk
#define NSLOT  4         // LDS ring slots
#define ROWSTR 208       // floats per LDS row

typedef float   f32x4 __attribute__((ext_vector_type(4)));
typedef short   s16x8 __attribute__((ext_vector_type(8)));
typedef _Float16 f16x2 __attribute__((ext_vector_type(2)));

__device__ ushort g_Wf[KSTEPS * FR_KS];   // [ks][ct][lane][8], RNE bf16

#define LOG2E 1.44269504f

__device__ __forceinline__ float fexp2(float x) {
#if __has_builtin(__builtin_amdgcn_exp2f)
    return __builtin_amdgcn_exp2f(x);
#else
    return exp2f(x);
#endif
}
__device__ __forceinline__ float frcp(float x) {
#if __has_builtin(__builtin_amdgcn_rcpf)
    return __builtin_amdgcn_rcpf(x);
#else
    return 1.0f / x;
#endif
}
__device__ __forceinline__ float fsigmoid(float x) {
    return frcp(1.0f + fexp2(-LOG2E * x));
}
__device__ __forceinline__ float ftanh2(float x) {
    return __builtin_fmaf(2.0f, frcp(1.0f + fexp2(-2.0f * LOG2E * x)), -1.0f);
}
__device__ __forceinline__ void ssleep() {
#if __has_builtin(__builtin_amdgcn_s_sleep)
    __builtin_amdgcn_s_sleep(8);
#endif
}
__device__ __forceinline__ void sbar0() {
#if __has_builtin(__builtin_amdgcn_sched_barrier)
    __builtin_amdgcn_sched_barrier(0);
#endif
}

// ---------------------------------------------------------------------------
// prep: W_ih -> frag-linear RNE bf16 g_Wf[ks][ct][lane][8] (2-term split).
// ---------------------------------------------------------------------------
__global__ void prep_w(const float* __restrict__ W) {
    int f = blockIdx.x * 256 + threadIdx.x;
    if (f >= KSTEPS * NCT * 64) return;
    const int l  = f & 63;
    const int ct = (f >> 6) % NCT;
    const int ks = (f >> 6) / NCT;
    const int n  = ct * 16 + (l & 15);
    const int k0 = ks * 32 + (l >> 4) * 8;
    ushort v[8] __attribute__((aligned(16)));
#pragma unroll
    for (int j = 0; j < 8; ++j) v[j] = 0;
    if (n < G4) {
        const float* wp = &W[(size_t)n * D_IN + k0];
#pragma unroll
        for (int j = 0; j < 8; ++j) {
            unsigned u = __float_as_uint(wp[j]);
            v[j] = (ushort)((u + 0x7FFFu + ((u >> 16) & 1u)) >> 16);  // RNE bf16
        }
    }
    *(uint4*)&g_Wf[(size_t)f * 8] = *(const uint4*)v;
}

__device__ __forceinline__ void pack2(float f0, float f1, unsigned& h, unsigned& l) {
    unsigned u0 = __float_as_uint(f0), u1 = __float_as_uint(f1);
    h = (u0 >> 16) | (u1 & 0xffff0000u);
    float d0 = f0 - __uint_as_float(u0 & 0xffff0000u);
    float d1 = f1 - __uint_as_float(u1 & 0xffff0000u);
    l = (__float_as_uint(d0) >> 16) | (__float_as_uint(d1) & 0xffff0000u);
}

#define REP25(M) M(0) M(1) M(2) M(3) M(4) M(5) M(6) M(7) M(8) M(9) \
                 M(10) M(11) M(12) M(13) M(14) M(15) M(16) M(17) M(18) M(19) \
                 M(20) M(21) M(22) M(23) M(24)

__device__ __forceinline__ unsigned pk2f16(float a, float b) {
#if __has_builtin(__builtin_amdgcn_cvt_pkrtz)
    return __builtin_bit_cast(unsigned, __builtin_amdgcn_cvt_pkrtz(a, b));
#else
    f16x2 v = {(_Float16)a, (_Float16)b};
    return __builtin_bit_cast(unsigned, v);
#endif
}

#if __has_builtin(__builtin_amdgcn_fdot2)
#define FD(hu_, wu_, cc_) __builtin_amdgcn_fdot2( \
    __builtin_bit_cast(f16x2, (hu_)), __builtin_bit_cast(f16x2, (wu_)), (cc_), false)
#else
#define FD(hu_, wu_, cc_) ((cc_) \
    + (float)__builtin_bit_cast(f16x2, (hu_))[0] * (float)__builtin_bit_cast(f16x2, (wu_))[0] \
    + (float)__builtin_bit_cast(f16x2, (hu_))[1] * (float)__builtin_bit_cast(f16x2, (wu_))[1])
#endif

// ---------------------------------------------------------------------------
// FUSED kernel: one block (8 waves) per batch. Wave 0 scans; waves 1-7
// produce xg chunks (32 time-rows) into a 4-slot LDS ring. GEMM runs in the
// scan's shadow -> its ~125 us leaves the critical path entirely.
// Sync: LDS ready[c] flags + done_upto back-pressure; ONE __syncthreads.
// ---------------------------------------------------------------------------
__global__ __launch_bounds__(512, 1) void lstm_fused(
    const float* __restrict__ x, const int* __restrict__ mask,
    const float* __restrict__ b_ih, const float* __restrict__ b_hh,
    const float* __restrict__ W_hh, const float* __restrict__ W_cls,
    const float* __restrict__ b_cls, float* __restrict__ out)
{
    __shared__ float ldsxg[NSLOT * CHROWS * ROWSTR];   // 106,496 B
    __shared__ int   s_flag[17];                       // [0..15]=ready, [16]=done_upto

    const int b    = blockIdx.x;
    const int tid  = threadIdx.x;
    const int wv   = tid >> 6;
    const int lane = tid & 63;

    // every wave computes len for this batch
    int s = 0;
#pragma unroll
    for (int k = 0; k < 8; ++k) s += mask[b * S_LEN + lane + 64 * k];
#pragma unroll
    for (int off = 1; off < 64; off <<= 1) s += __shfl_xor(s, off, 64);
    const int len = s;                               // >= 1
    const int NCc = (len + CHROWS - 1) >> 5;         // chunks

    if (tid < 17) s_flag[tid] = 0;
    __syncthreads();                                 // the ONLY block barrier

    volatile int* vflag = s_flag;

    if (wv != 0) {
        // ---------------- producers (waves 1..7) ----------------
        const int lr  = lane & 15;
        const int kch = (lane >> 4) * 8;
        for (int c = wv - 1; c < NCc; c += 7) {
            const int r0 = c * CHROWS;
            const float* xr0 = x + ((size_t)b * S_LEN + r0 + lr) * D_IN;
            const float* xr1 = xr0 + (size_t)16 * D_IN;

            f32x4 acc0[NCT], acc1[NCT];
#pragma unroll
            for (int i = 0; i < NCT; ++i) {
                acc0[i] = (f32x4){0.f, 0.f, 0.f, 0.f};
                acc1[i] = (f32x4){0.f, 0.f, 0.f, 0.f};
            }
            float4 ac0 = *(const float4*)(xr0 + kch);
            float4 ac1 = *(const float4*)(xr0 + kch + 4);
            float4 ac2 = *(const float4*)(xr1 + kch);
            float4 ac3 = *(const float4*)(xr1 + kch + 4);
            float4 an0, an1, an2, an3;

            for (int ks = 0; ks < KSTEPS; ++ks) {
                if (ks < KSTEPS - 1) {               // 1-deep A prefetch (HBM)
                    const int k1 = (ks + 1) * 32 + kch;
                    an0 = *(const float4*)(xr0 + k1);
                    an1 = *(const float4*)(xr0 + k1 + 4);
                    an2 = *(const float4*)(xr1 + k1);
                    an3 = *(const float4*)(xr1 + k1 + 4);
                }
                uint4 h0, l0, h1, l1;
                pack2(ac0.x, ac0.y, h0.x, l0.x); pack2(ac0.z, ac0.w, h0.y, l0.y);
                pack2(ac1.x, ac1.y, h0.z, l0.z); pack2(ac1.z, ac1.w, h0.w, l0.w);
                pack2(ac2.x, ac2.y, h1.x, l1.x); pack2(ac2.z, ac2.w, h1.y, l1.y);
                pack2(ac3.x, ac3.y, h1.z, l1.z); pack2(ac3.z, ac3.w, h1.w, l1.w);
                s16x8 A0h = *(s16x8*)&h0, A0l = *(s16x8*)&l0;
                s16x8 A1h = *(s16x8*)&h1, A1l = *(s16x8*)&l1;
                const ushort* bp = g_Wf + (size_t)ks * FR_KS + lane * 8;
#pragma unroll
                for (int ct = 0; ct < NCT; ++ct) {   // B direct from L2
                    s16x8 Bh = *(const s16x8*)(bp + ct * 512);
                    acc0[ct] = __builtin_amdgcn_mfma_f32_16x16x32_bf16(A0h, Bh, acc0[ct], 0, 0, 0);
                    acc0[ct] = __builtin_amdgcn_mfma_f32_16x16x32_bf16(A0l, Bh, acc0[ct], 0, 0, 0);
                    acc1[ct] = __builtin_amdgcn_mfma_f32_16x16x32_bf16(A1h, Bh, acc1[ct], 0, 0, 0);
                    acc1[ct] = __builtin_amdgcn_mfma_f32_16x16x32_bf16(A1l, Bh, acc1[ct], 0, 0, 0);
                }
                ac0 = an0; ac1 = an1; ac2 = an2; ac3 = an3;
            }

            // back-pressure: slot (c&3) free once scanner finished chunk c-4
            if (c >= NSLOT) {
                while (vflag[16] < c - (NSLOT - 1)) ssleep();
            }
            float* slot = ldsxg + (size_t)(c & (NSLOT - 1)) * (CHROWS * ROWSTR);
            const int orow = (lane >> 4) * 4;
#pragma unroll
            for (int ct = 0; ct < NCT; ++ct) {
                const int n = ct * 16 + (lane & 15);
                if (n < G4) {
                    const int g = n / 50, j = n - g * 50;
                    const int off = j * 4 + g;       // [j][gate]
                    const float bias = b_ih[n] + b_hh[n];
#pragma unroll
                    for (int e = 0; e < 4; ++e) {
                        slot[(orow + e) * ROWSTR + off]      = acc0[ct][e] + bias;
                        slot[(orow + 16 + e) * ROWSTR + off] = acc1[ct][e] + bias;
                    }
                }
            }
            asm volatile("s_waitcnt lgkmcnt(0)" ::: "memory");  // data before flag
            if (lane == 0) vflag[c] = 1;
        }
        return;                                      // producers done
    }

    // ---------------- scanner (wave 0) ----------------
    const bool act = (lane < H_DIM);
    const int  l   = lane;
    const int  ll  = act ? lane : 0;
    const float* wr0 = W_hh + (size_t)ll * H_DIM;
    const float* wr1 = W_hh + (size_t)(50 + ll) * H_DIM;
    const float* wr2 = W_hh + (size_t)(100 + ll) * H_DIM;
    const float* wr3 = W_hh + (size_t)(150 + ll) * H_DIM;

#define WDECL(q) unsigned wi_##q, wf_##q, wg_##q, wo_##q;
    REP25(WDECL)
#undef WDECL
#define WLOAD(q) \
    wi_##q = pk2f16(wr0[2*q], wr0[2*q+1]); \
    wf_##q = pk2f16(wr1[2*q], wr1[2*q+1]); \
    wg_##q = pk2f16(wr2[2*q], wr2[2*q+1]); \
    wo_##q = pk2f16(wr3[2*q], wr3[2*q+1]);
    REP25(WLOAD)
#undef WLOAD
#define WPIN(q) asm volatile("" : "+v"(wi_##q), "+v"(wf_##q), "+v"(wg_##q), "+v"(wo_##q));
    REP25(WPIN)
#undef WPIN

    float h = 0.f, c = 0.f;

    auto step = [&](float4& v, const float* slot, int nextrow) {
#if __has_builtin(__builtin_amdgcn_mov_dpp)
        int hsw = __builtin_amdgcn_mov_dpp(__float_as_int(h), 0xB1, 0xF, 0xF, true);
#else
        int hsw = __float_as_int(__shfl_xor(h, 1, 64));
#endif
        unsigned hu = pk2f16(h, __int_as_float(hsw));

        float ai0 = v.x, af0 = v.y, aq0 = v.z, ao0 = v.w;
        float ai1 = 0.f, af1 = 0.f, aq1 = 0.f, ao1 = 0.f;

#define RDECL(q) unsigned r_##q = (unsigned)__builtin_amdgcn_readlane((int)hu, 2*q);
        REP25(RDECL)
#undef RDECL
#define DOTA(q) { ai0 = FD(r_##q, wi_##q, ai0); af0 = FD(r_##q, wf_##q, af0); \
                  aq0 = FD(r_##q, wg_##q, aq0); ao0 = FD(r_##q, wo_##q, ao0); }
#define DOTB(q) { ai1 = FD(r_##q, wi_##q, ai1); af1 = FD(r_##q, wf_##q, af1); \
                  aq1 = FD(r_##q, wg_##q, aq1); ao1 = FD(r_##q, wo_##q, ao1); }
        DOTA(0)  DOTB(1)  DOTA(2)  DOTB(3)  DOTA(4)
        DOTB(5)  DOTA(6)  DOTB(7)  DOTA(8)  DOTB(9)
        DOTA(10) DOTB(11) DOTA(12) DOTB(13) DOTA(14)
        DOTB(15) DOTA(16) DOTB(17) DOTA(18) DOTB(19)
        DOTA(20) DOTB(21) DOTA(22) DOTB(23) DOTA(24)
#undef DOTA
#undef DOTB
        float ai = ai0 + ai1, af = af0 + af1;
        float aq = aq0 + aq1, ao = ao0 + ao1;

        sbar0();
        v = *(const float4*)(slot + nextrow * ROWSTR + ll * 4);  // ds_read_b128
        sbar0();

        float ig = fsigmoid(ai), fg = fsigmoid(af);
        float gg = ftanh2(aq),   og = fsigmoid(ao);
        c = fg * c + ig * gg;
        h = og * ftanh2(c);
    };

    for (int cc = 0; cc < NCc; ++cc) {
        while (vflag[cc] == 0) ssleep();             // wait for chunk
        const float* slot = ldsxg + (size_t)(cc & (NSLOT - 1)) * (CHROWS * ROWSTR);
        const int n = (cc == NCc - 1) ? (len - cc * CHROWS) : CHROWS;

        float4 vA = *(const float4*)(slot + 0 * ROWSTR + ll * 4);
        float4 vB = *(const float4*)(slot + (n > 1 ? 1 : 0) * ROWSTR + ll * 4);

        int tl = 0;
        while (tl < n) {
            { int nr = tl + 2 < n ? tl + 2 : n - 1; step(vA, slot, nr); }
            ++tl; if (tl >= n) break;
            { int nr = tl + 2 < n ? tl + 2 : n - 1; step(vB, slot, nr); }
            ++tl;
        }
        if (lane == 0) vflag[16] = cc + 1;           // release slot
    }

    float p0 = act ? h * W_cls[l]          : 0.f;
    float p1 = act ? h * W_cls[H_DIM + l]  : 0.f;
#pragma unroll
    for (int off = 1; off < 64; off <<= 1) {
        p0 += __shfl_xor(p0, off, 64);
        p1 += __shfl_xor(p1, off, 64);
    }
    if (lane == 0) {
        out[2 * b]     = p0 + b_cls[0];
        out[2 * b + 1] = p1 + b_cls[1];
    }
}

extern "C" void kernel_launch(void* const* d_in, const int* in_sizes, int n_in,
                              void* d_out, int out_size, void* d_ws, size_t ws_size,
                              hipStream_t stream) {
    const float* x     = (const float*)d_in[0];
    const int*   mask  = (const int*)  d_in[1];
    const float* W_ih  = (const float*)d_in[2];
    const float* W_hh  = (const float*)d_in[3];
    const float* b_ih  = (const float*)d_in[4];
    const float* b_hh  = (const float*)d_in[5];
    const float* W_cls = (const float*)d_in[6];
    const float* b_cls = (const float*)d_in[7];
    float* out = (float*)d_out;

    hipLaunchKernelGGL(prep_w, dim3(78), dim3(256), 0, stream, W_ih);
    hipLaunchKernelGGL(lstm_fused, dim3(256), dim3(512), 0, stream,
                       x, mask, b_ih, b_hh, W_hh, W_cls, b_cls, out);
}

// Round 15
// 287.063 us; speedup vs baseline: 1.2270x; 1.0088x over previous
//
#include <hip/hip_runtime.h>
#include <math.h>

#define S_LEN 512
#define D_IN  768
#define H_DIM 50
#define G4    200
#define NCT   13
#define KSTEPS 24        // 768/32
#define FR_KS  6656      // ushorts per K-step: 13 ct x 64 lanes x 8
#define CHROWS 32        // rows per chunk
#define NSLOT  4         // LDS ring slots
#define ROWSTR 208       // floats per LDS row

typedef float   f32x4 __attribute__((ext_vector_type(4)));
typedef short   s16x8 __attribute__((ext_vector_type(8)));
typedef _Float16 f16x2 __attribute__((ext_vector_type(2)));

__device__ ushort g_Wf[KSTEPS * FR_KS];   // [ks][ct][lane][8], RNE bf16

#define LOG2E 1.44269504f

__device__ __forceinline__ float fexp2(float x) {
#if __has_builtin(__builtin_amdgcn_exp2f)
    return __builtin_amdgcn_exp2f(x);
#else
    return exp2f(x);
#endif
}
__device__ __forceinline__ float frcp(float x) {
#if __has_builtin(__builtin_amdgcn_rcpf)
    return __builtin_amdgcn_rcpf(x);
#else
    return 1.0f / x;
#endif
}
__device__ __forceinline__ float fsigmoid(float x) {
    return frcp(1.0f + fexp2(-LOG2E * x));
}
__device__ __forceinline__ float ftanh2(float x) {
    return __builtin_fmaf(2.0f, frcp(1.0f + fexp2(-2.0f * LOG2E * x)), -1.0f);
}
__device__ __forceinline__ void ssleep() {
#if __has_builtin(__builtin_amdgcn_s_sleep)
    __builtin_amdgcn_s_sleep(8);
#endif
}
__device__ __forceinline__ void sbar0() {
#if __has_builtin(__builtin_amdgcn_sched_barrier)
    __builtin_amdgcn_sched_barrier(0);
#endif
}
__device__ __forceinline__ void setprio(int p) {
    if (p == 0) __builtin_amdgcn_s_setprio(0);
    else        __builtin_amdgcn_s_setprio(1);
}

// ---------------------------------------------------------------------------
// prep: W_ih -> frag-linear RNE bf16 g_Wf[ks][ct][lane][8] (2-term split).
// ---------------------------------------------------------------------------
__global__ void prep_w(const float* __restrict__ W) {
    int f = blockIdx.x * 256 + threadIdx.x;
    if (f >= KSTEPS * NCT * 64) return;
    const int l  = f & 63;
    const int ct = (f >> 6) % NCT;
    const int ks = (f >> 6) / NCT;
    const int n  = ct * 16 + (l & 15);
    const int k0 = ks * 32 + (l >> 4) * 8;
    ushort v[8] __attribute__((aligned(16)));
#pragma unroll
    for (int j = 0; j < 8; ++j) v[j] = 0;
    if (n < G4) {
        const float* wp = &W[(size_t)n * D_IN + k0];
#pragma unroll
        for (int j = 0; j < 8; ++j) {
            unsigned u = __float_as_uint(wp[j]);
            v[j] = (ushort)((u + 0x7FFFu + ((u >> 16) & 1u)) >> 16);  // RNE bf16
        }
    }
    *(uint4*)&g_Wf[(size_t)f * 8] = *(const uint4*)v;
}

__device__ __forceinline__ void pack2(float f0, float f1, unsigned& h, unsigned& l) {
    unsigned u0 = __float_as_uint(f0), u1 = __float_as_uint(f1);
    h = (u0 >> 16) | (u1 & 0xffff0000u);
    float d0 = f0 - __uint_as_float(u0 & 0xffff0000u);
    float d1 = f1 - __uint_as_float(u1 & 0xffff0000u);
    l = (__float_as_uint(d0) >> 16) | (__float_as_uint(d1) & 0xffff0000u);
}

#define REP25(M) M(0) M(1) M(2) M(3) M(4) M(5) M(6) M(7) M(8) M(9) \
                 M(10) M(11) M(12) M(13) M(14) M(15) M(16) M(17) M(18) M(19) \
                 M(20) M(21) M(22) M(23) M(24)

__device__ __forceinline__ unsigned pk2f16(float a, float b) {
#if __has_builtin(__builtin_amdgcn_cvt_pkrtz)
    return __builtin_bit_cast(unsigned, __builtin_amdgcn_cvt_pkrtz(a, b));
#else
    f16x2 v = {(_Float16)a, (_Float16)b};
    return __builtin_bit_cast(unsigned, v);
#endif
}

#if __has_builtin(__builtin_amdgcn_fdot2)
#define FD(hu_, wu_, cc_) __builtin_amdgcn_fdot2( \
    __builtin_bit_cast(f16x2, (hu_)), __builtin_bit_cast(f16x2, (wu_)), (cc_), false)
#else
#define FD(hu_, wu_, cc_) ((cc_) \
    + (float)__builtin_bit_cast(f16x2, (hu_))[0] * (float)__builtin_bit_cast(f16x2, (wu_))[0] \
    + (float)__builtin_bit_cast(f16x2, (hu_))[1] * (float)__builtin_bit_cast(f16x2, (wu_))[1])
#endif

// ---------------------------------------------------------------------------
// FUSED kernel: one block (8 waves) per batch. Wave 0 scans at s_setprio(1);
// waves 1-7 produce xg chunks into a 4-slot LDS ring at setprio(0). R14
// showed the GEMM hides but SIMD issue contention slowed the scanner's
// serial chain ~40%; priority arbitration gives the scanner every slot it
// can use and producers fill true stalls only.
// ---------------------------------------------------------------------------
__global__ __launch_bounds__(512, 1) void lstm_fused(
    const float* __restrict__ x, const int* __restrict__ mask,
    const float* __restrict__ b_ih, const float* __restrict__ b_hh,
    const float* __restrict__ W_hh, const float* __restrict__ W_cls,
    const float* __restrict__ b_cls, float* __restrict__ out)
{
    __shared__ float ldsxg[NSLOT * CHROWS * ROWSTR];   // 106,496 B
    __shared__ int   s_flag[17];                       // [0..15]=ready, [16]=done_upto

    const int b    = blockIdx.x;
    const int tid  = threadIdx.x;
    const int wv   = tid >> 6;
    const int lane = tid & 63;

    int s = 0;
#pragma unroll
    for (int k = 0; k < 8; ++k) s += mask[b * S_LEN + lane + 64 * k];
#pragma unroll
    for (int off = 1; off < 64; off <<= 1) s += __shfl_xor(s, off, 64);
    const int len = s;                               // >= 1
    const int NCc = (len + CHROWS - 1) >> 5;         // chunks

    if (tid < 17) s_flag[tid] = 0;
    __syncthreads();                                 // the ONLY block barrier

    volatile int* vflag = s_flag;

    if (wv != 0) {
        // ---------------- producers (waves 1..7), low priority ----------------
        setprio(0);
        const int lr  = lane & 15;
        const int kch = (lane >> 4) * 8;
        for (int c = wv - 1; c < NCc; c += 7) {
            const int r0 = c * CHROWS;
            const float* xr0 = x + ((size_t)b * S_LEN + r0 + lr) * D_IN;
            const float* xr1 = xr0 + (size_t)16 * D_IN;

            f32x4 acc0[NCT], acc1[NCT];
#pragma unroll
            for (int i = 0; i < NCT; ++i) {
                acc0[i] = (f32x4){0.f, 0.f, 0.f, 0.f};
                acc1[i] = (f32x4){0.f, 0.f, 0.f, 0.f};
            }
            float4 ac0 = *(const float4*)(xr0 + kch);
            float4 ac1 = *(const float4*)(xr0 + kch + 4);
            float4 ac2 = *(const float4*)(xr1 + kch);
            float4 ac3 = *(const float4*)(xr1 + kch + 4);
            float4 an0, an1, an2, an3;

            for (int ks = 0; ks < KSTEPS; ++ks) {
                if (ks < KSTEPS - 1) {               // 1-deep A prefetch (HBM)
                    const int k1 = (ks + 1) * 32 + kch;
                    an0 = *(const float4*)(xr0 + k1);
                    an1 = *(const float4*)(xr0 + k1 + 4);
                    an2 = *(const float4*)(xr1 + k1);
                    an3 = *(const float4*)(xr1 + k1 + 4);
                }
                uint4 h0, l0, h1, l1;
                pack2(ac0.x, ac0.y, h0.x, l0.x); pack2(ac0.z, ac0.w, h0.y, l0.y);
                pack2(ac1.x, ac1.y, h0.z, l0.z); pack2(ac1.z, ac1.w, h0.w, l0.w);
                pack2(ac2.x, ac2.y, h1.x, l1.x); pack2(ac2.z, ac2.w, h1.y, l1.y);
                pack2(ac3.x, ac3.y, h1.z, l1.z); pack2(ac3.z, ac3.w, h1.w, l1.w);
                s16x8 A0h = *(s16x8*)&h0, A0l = *(s16x8*)&l0;
                s16x8 A1h = *(s16x8*)&h1, A1l = *(s16x8*)&l1;
                const ushort* bp = g_Wf + (size_t)ks * FR_KS + lane * 8;
#pragma unroll
                for (int ct = 0; ct < NCT; ++ct) {   // B direct from L2
                    s16x8 Bh = *(const s16x8*)(bp + ct * 512);
                    acc0[ct] = __builtin_amdgcn_mfma_f32_16x16x32_bf16(A0h, Bh, acc0[ct], 0, 0, 0);
                    acc0[ct] = __builtin_amdgcn_mfma_f32_16x16x32_bf16(A0l, Bh, acc0[ct], 0, 0, 0);
                    acc1[ct] = __builtin_amdgcn_mfma_f32_16x16x32_bf16(A1h, Bh, acc1[ct], 0, 0, 0);
                    acc1[ct] = __builtin_amdgcn_mfma_f32_16x16x32_bf16(A1l, Bh, acc1[ct], 0, 0, 0);
                }
                ac0 = an0; ac1 = an1; ac2 = an2; ac3 = an3;
            }

            if (c >= NSLOT) {
                while (vflag[16] < c - (NSLOT - 1)) ssleep();
            }
            float* slot = ldsxg + (size_t)(c & (NSLOT - 1)) * (CHROWS * ROWSTR);
            const int orow = (lane >> 4) * 4;
#pragma unroll
            for (int ct = 0; ct < NCT; ++ct) {
                const int n = ct * 16 + (lane & 15);
                if (n < G4) {
                    const int g = n / 50, j = n - g * 50;
                    const int off = j * 4 + g;       // [j][gate]
                    const float bias = b_ih[n] + b_hh[n];
#pragma unroll
                    for (int e = 0; e < 4; ++e) {
                        slot[(orow + e) * ROWSTR + off]      = acc0[ct][e] + bias;
                        slot[(orow + 16 + e) * ROWSTR + off] = acc1[ct][e] + bias;
                    }
                }
            }
            asm volatile("s_waitcnt lgkmcnt(0)" ::: "memory");  // data before flag
            if (lane == 0) vflag[c] = 1;
        }
        return;
    }

    // ---------------- scanner (wave 0), high priority ----------------
    setprio(1);
    const bool act = (lane < H_DIM);
    const int  l   = lane;
    const int  ll  = act ? lane : 0;
    const float* wr0 = W_hh + (size_t)ll * H_DIM;
    const float* wr1 = W_hh + (size_t)(50 + ll) * H_DIM;
    const float* wr2 = W_hh + (size_t)(100 + ll) * H_DIM;
    const float* wr3 = W_hh + (size_t)(150 + ll) * H_DIM;

#define WDECL(q) unsigned wi_##q, wf_##q, wg_##q, wo_##q;
    REP25(WDECL)
#undef WDECL
#define WLOAD(q) \
    wi_##q = pk2f16(wr0[2*q], wr0[2*q+1]); \
    wf_##q = pk2f16(wr1[2*q], wr1[2*q+1]); \
    wg_##q = pk2f16(wr2[2*q], wr2[2*q+1]); \
    wo_##q = pk2f16(wr3[2*q], wr3[2*q+1]);
    REP25(WLOAD)
#undef WLOAD
#define WPIN(q) asm volatile("" : "+v"(wi_##q), "+v"(wf_##q), "+v"(wg_##q), "+v"(wo_##q));
    REP25(WPIN)
#undef WPIN

    float h = 0.f, c = 0.f;

    auto step = [&](float4& v, const float* slot, int nextrow) {
#if __has_builtin(__builtin_amdgcn_mov_dpp)
        int hsw = __builtin_amdgcn_mov_dpp(__float_as_int(h), 0xB1, 0xF, 0xF, true);
#else
        int hsw = __float_as_int(__shfl_xor(h, 1, 64));
#endif
        unsigned hu = pk2f16(h, __int_as_float(hsw));

        float ai0 = v.x, af0 = v.y, aq0 = v.z, ao0 = v.w;
        float ai1 = 0.f, af1 = 0.f, aq1 = 0.f, ao1 = 0.f;

#define RDECL(q) unsigned r_##q = (unsigned)__builtin_amdgcn_readlane((int)hu, 2*q);
        REP25(RDECL)
#undef RDECL
#define DOTA(q) { ai0 = FD(r_##q, wi_##q, ai0); af0 = FD(r_##q, wf_##q, af0); \
                  aq0 = FD(r_##q, wg_##q, aq0); ao0 = FD(r_##q, wo_##q, ao0); }
#define DOTB(q) { ai1 = FD(r_##q, wi_##q, ai1); af1 = FD(r_##q, wf_##q, af1); \
                  aq1 = FD(r_##q, wg_##q, aq1); ao1 = FD(r_##q, wo_##q, ao1); }
        DOTA(0)  DOTB(1)  DOTA(2)  DOTB(3)  DOTA(4)
        DOTB(5)  DOTA(6)  DOTB(7)  DOTA(8)  DOTB(9)
        DOTA(10) DOTB(11) DOTA(12) DOTB(13) DOTA(14)
        DOTB(15) DOTA(16) DOTB(17) DOTA(18) DOTB(19)
        DOTA(20) DOTB(21) DOTA(22) DOTB(23) DOTA(24)
#undef DOTA
#undef DOTB
        float ai = ai0 + ai1, af = af0 + af1;
        float aq = aq0 + aq1, ao = ao0 + ao1;

        sbar0();
        v = *(const float4*)(slot + nextrow * ROWSTR + ll * 4);  // ds_read_b128
        sbar0();

        float ig = fsigmoid(ai), fg = fsigmoid(af);
        float gg = ftanh2(aq),   og = fsigmoid(ao);
        c = fg * c + ig * gg;
        h = og * ftanh2(c);
    };

    for (int cc = 0; cc < NCc; ++cc) {
        while (vflag[cc] == 0) ssleep();             // wait for chunk
        const float* slot = ldsxg + (size_t)(cc & (NSLOT - 1)) * (CHROWS * ROWSTR);
        const int n = (cc == NCc - 1) ? (len - cc * CHROWS) : CHROWS;

        float4 vA = *(const float4*)(slot + 0 * ROWSTR + ll * 4);
        float4 vB = *(const float4*)(slot + (n > 1 ? 1 : 0) * ROWSTR + ll * 4);

        int tl = 0;
        while (tl < n) {
            { int nr = tl + 2 < n ? tl + 2 : n - 1; step(vA, slot, nr); }
            ++tl; if (tl >= n) break;
            { int nr = tl + 2 < n ? tl + 2 : n - 1; step(vB, slot, nr); }
            ++tl;
        }
        if (lane == 0) vflag[16] = cc + 1;           // release slot
    }

    float p0 = act ? h * W_cls[l]          : 0.f;
    float p1 = act ? h * W_cls[H_DIM + l]  : 0.f;
#pragma unroll
    for (int off = 1; off < 64; off <<= 1) {
        p0 += __shfl_xor(p0, off, 64);
        p1 += __shfl_xor(p1, off, 64);
    }
    if (lane == 0) {
        out[2 * b]     = p0 + b_cls[0];
        out[2 * b + 1] = p1 + b_cls[1];
    }
}

extern "C" void kernel_launch(void* const* d_in, const int* in_sizes, int n_in,
                              void* d_out, int out_size, void* d_ws, size_t ws_size,
                              hipStream_t stream) {
    const float* x     = (const float*)d_in[0];
    const int*   mask  = (const int*)  d_in[1];
    const float* W_ih  = (const float*)d_in[2];
    const float* W_hh  = (const float*)d_in[3];
    const float* b_ih  = (const float*)d_in[4];
    const float* b_hh  = (const float*)d_in[5];
    const float* W_cls = (const float*)d_in[6];
    const float* b_cls = (const float*)d_in[7];
    float* out = (float*)d_out;

    hipLaunchKernelGGL(prep_w, dim3(78), dim3(256), 0, stream, W_ih);
    hipLaunchKernelGGL(lstm_fused, dim3(256), dim3(512), 0, stream,
                       x, mask, b_ih, b_hh, W_hh, W_cls, b_cls, out);
}